// Round 7
// baseline (520.027 us; speedup 1.0000x reference)
//
#include <hip/hip_runtime.h>
#include <math.h>

typedef __attribute__((ext_vector_type(8))) short short8;
typedef __attribute__((ext_vector_type(4))) float float4v;
typedef __attribute__((ext_vector_type(16))) float float16v;
typedef __attribute__((ext_vector_type(4))) unsigned short ushort4v;
typedef unsigned short u16;
typedef unsigned int u32;

#define NB 64
#define NN 2048
#define FD 128
#define UD 64
#define KT 384

// ---- PANEL FORMAT (all GEMM operands) ----
// matrix[row][k] -> flat[(rowgrp*KGRPS + kgrp)*1024 + (((k>>3)&3)*32 + (row&31))*8 + (k&7)]
// One 32x32 panel = 2KB contiguous; slot order == MFMA fragment order (lane=row, 16B/lane).

__device__ __forceinline__ u16 f2bf(float f) {
    unsigned int u = __float_as_uint(f);
    u += 0x7fffu + ((u >> 16) & 1u);
    return (u16)(u >> 16);
}
__device__ __forceinline__ float bf2f(u16 s) {
    return __uint_as_float(((unsigned int)s) << 16);
}
__device__ __forceinline__ float sigmoidf_(float x) {
    return 1.0f / (1.0f + expf(-x));
}
__device__ __forceinline__ void gl2lds16(const u16* g, u16* l) {
    __builtin_amdgcn_global_load_lds((const __attribute__((address_space(1))) unsigned int*)g,
                                     (__attribute__((address_space(3))) unsigned int*)l,
                                     16, 0, 0);
}

// ---------------------------------------------------------------- rownorm
__global__ void k_rownorm(const float* __restrict__ adj, float* __restrict__ d_inv) {
    int m = blockIdx.x;
    const float4v* row = (const float4v*)(adj + (size_t)m * NN);
    float s = 0.f;
    for (int i = threadIdx.x; i < NN / 4; i += 256) {
        float4v v = row[i];
        s += v.x + v.y + v.z + v.w;
    }
    __shared__ float red[4];
    for (int off = 32; off; off >>= 1) s += __shfl_down(s, off, 64);
    if ((threadIdx.x & 63) == 0) red[threadIdx.x >> 6] = s;
    __syncthreads();
    if (threadIdx.x == 0) {
        float t = red[0] + red[1] + red[2] + red[3] + 1.0f;
        d_inv[m] = 1.0f / t;
    }
}

// ---------------------------------------------------------------- adjT panels (rows n, k=m)
__global__ void k_adjT(const float* __restrict__ adj, const float* __restrict__ d_inv,
                       u16* __restrict__ adjT) {
    __shared__ u16 T[64 * 72];
    int m0 = blockIdx.x * 64;
    int n0 = blockIdx.y * 64;
    int t = threadIdx.x;
    for (int p = 0; p < 4; ++p) {
        int idx = t + 256 * p;
        int i  = idx >> 4;
        int n4 = idx & 15;
        int m = m0 + i;
        float4v v = *(const float4v*)(adj + (size_t)m * NN + n0 + n4 * 4);
        float di = d_inv[m];
        float vv[4] = {v.x, v.y, v.z, v.w};
#pragma unroll
        for (int j = 0; j < 4; ++j) {
            int n = n0 + n4 * 4 + j;
            float a = vv[j] + ((m == n) ? 1.0f : 0.0f);
            T[(n4 * 4 + j) * 72 + i] = f2bf(a * di);
        }
    }
    __syncthreads();
#pragma unroll
    for (int p = 0; p < 2; ++p) {
        int S = t + 256 * p;
        int rgl = S >> 8, kgl = (S >> 7) & 1, s = S & 127;
        int c = s >> 5, r = s & 31;
        short8 v = *(const short8*)(T + (rgl * 32 + r) * 72 + kgl * 32 + c * 8);
        *(short8*)(adjT + ((size_t)((n0 >> 5) + rgl) * 64 + (m0 >> 5) + kgl) * 1024 + s * 8) = v;
    }
}

// ---------------------------------------------------------------- W -> panels (rows o, k=kp=kd*128+f)
__global__ void k_reorderW(const float* __restrict__ W, u16* __restrict__ Wt, int OD) {
    int idx = blockIdx.x * 256 + threadIdx.x;
    if (idx >= KT * OD) return;
    int o  = idx % OD;
    int kp = idx / OD;
    int kd = kp >> 7, f = kp & 127;
    size_t dst = ((size_t)(o >> 5) * 12 + (kp >> 5)) * 1024 + (((kp >> 3) & 3) * 32 + (o & 31)) * 8 + (kp & 7);
    Wt[dst] = f2bf(W[(size_t)(f * 3 + kd) * OD + o]);
}

// ---------------------------------------------------------------- xcat: X0f panels (rows b*128+f,k=m) + X0m panels (rows m per b,k=f)
__global__ void k_xcat(const float* __restrict__ x, const float* __restrict__ h,
                       u16* __restrict__ X0f, u16* __restrict__ X0m) {
    __shared__ u16 T[128 * 136];
    int m0 = blockIdx.x * 128;
    int b  = blockIdx.y;
    int t = threadIdx.x;
    const float* srcs[2] = { x + (size_t)b * (NN * 64), h + (size_t)b * (NN * 64) };
    for (int s = 0; s < 2; ++s) {
        const float* src = srcs[s];
        for (int p = 0; p < 8; ++p) {
            int idx = t + 256 * p;
            int mi = idx >> 4;
            int f4 = idx & 15;
            float4v v = *(const float4v*)(src + (size_t)(m0 + mi) * 64 + f4 * 4);
            float vv[4] = {v.x, v.y, v.z, v.w};
#pragma unroll
            for (int j = 0; j < 4; ++j)
                T[(s * 64 + f4 * 4 + j) * 136 + mi] = f2bf(vv[j]);
        }
    }
    __syncthreads();
    // X0f: 16 panels (4 fg x 4 kg)
#pragma unroll
    for (int p = 0; p < 8; ++p) {
        int S = t + 256 * p;
        int fgl = S >> 9, kgl = (S >> 7) & 3, s = S & 127;
        int c = s >> 5, r = s & 31;
        short8 v = *(const short8*)(T + (fgl * 32 + r) * 136 + kgl * 32 + c * 8);
        *(short8*)(X0f + ((size_t)(b * 4 + fgl) * 64 + (m0 >> 5) + kgl) * 1024 + s * 8) = v;
    }
    // X0m: 16 panels (4 mg x 4 fg): slot(m,f-chunk), column reads from T
#pragma unroll
    for (int p = 0; p < 8; ++p) {
        int S = t + 256 * p;           // 0..2047
        int fc = S >> 7;               // f-chunk 0..15
        int mi = S & 127;
        short8 v;
#pragma unroll
        for (int e = 0; e < 8; ++e) v[e] = (short)T[(fc * 8 + e) * 136 + mi];
        size_t dst = ((size_t)(b * 64 + (m0 >> 5) + (mi >> 5)) * 4 + (fc >> 2)) * 1024
                     + ((fc & 3) * 32 + (mi & 31)) * 8;
        *(short8*)(X0m + dst) = v;
    }
}

// ---------------------------------------------------------------- GEMM, (64*MT)x128 tile, 32x32x16 MFMA
// A: adjT (N-op). Bc: [row][m] panels (M-op). Outputs:
//   outM (always): m-major panels [b][m][f], direct from regs (coalesced 1KB/instr)
//   outF (optional): [row][m] panels via LDS transpose (for next GEMM's B-input)
// mode 1: 2*acc - Sub (Sub in m-major layout). grid (cBlocks,16), cBlocks=NC/(64*MT)
template<int MT>
__global__ __launch_bounds__(256, 2)
void k_gemm(const u16* __restrict__ A, const u16* __restrict__ Bc,
            u16* __restrict__ outF, u16* __restrict__ outM,
            const u16* __restrict__ Sub, int mode, int cBlocks) {
    __shared__ u16 SM[8192 + 4096 * MT];
    u16* A0 = SM;            u16* A1 = SM + 4096;
    u16* B0 = SM + 8192;     u16* B1 = SM + 8192 + 2048 * MT;

    int id = blockIdx.x + cBlocks * blockIdx.y;
    int band = cBlocks >> 3;
    int g = id & 7, s = id >> 3;
    int cb = g * band + (s % band);
    int nb = s / band;
    int c0 = cb * (64 * MT);
    int n0 = nb * 128;

    int t = threadIdx.x;
    int wave = t >> 6, lane = t & 63;
    int wy = wave & 1, wx = wave >> 1;
    int ln = lane & 31, hi = lane >> 5;
    int l16 = lane * 8;

    const u16* gaP[2];
#pragma unroll
    for (int i = 0; i < 2; ++i) {
        int T = t + 256 * i;
        gaP[i] = A + ((size_t)((n0 >> 5) + (T >> 7)) * 64) * 1024 + (size_t)(T & 127) * 8;
    }
    const u16* gbP[MT];
#pragma unroll
    for (int i = 0; i < MT; ++i) {
        int T = t + 256 * i;
        gbP[i] = Bc + ((size_t)((c0 >> 5) + (T >> 7)) * 64) * 1024 + (size_t)(T & 127) * 8;
    }

    float16v acc[MT][2];
#pragma unroll
    for (int i = 0; i < MT; ++i)
#pragma unroll
        for (int j = 0; j < 2; ++j)
#pragma unroll
            for (int e = 0; e < 16; ++e) acc[i][j][e] = 0.f;

#pragma unroll
    for (int i = 0; i < 2; ++i)  gl2lds16(gaP[i], A0 + (t + 256 * i) * 8);
#pragma unroll
    for (int i = 0; i < MT; ++i) gl2lds16(gbP[i], B0 + (t + 256 * i) * 8);

#pragma unroll 2
    for (int it = 0; it < 64; ++it) {
        u16* Ac = (it & 1) ? A1 : A0;
        u16* Bs = (it & 1) ? B1 : B0;
        __syncthreads();
        if (it + 1 < 64) {
            int ko = (it + 1) * 1024;
            u16* An = (it & 1) ? A0 : A1;
            u16* Bn = (it & 1) ? B0 : B1;
#pragma unroll
            for (int i = 0; i < 2; ++i)  gl2lds16(gaP[i] + ko, An + (t + 256 * i) * 8);
#pragma unroll
            for (int i = 0; i < MT; ++i) gl2lds16(gbP[i] + ko, Bn + (t + 256 * i) * 8);
        }
        short8 fa[2][MT], fb[2][2];
#pragma unroll
        for (int ks = 0; ks < 2; ++ks) {
#pragma unroll
            for (int mt = 0; mt < MT; ++mt)
                fa[ks][mt] = *(const short8*)(Bs + ((wx * MT + mt) * 2 + ks) * 512 + l16);
#pragma unroll
            for (int nt = 0; nt < 2; ++nt)
                fb[ks][nt] = *(const short8*)(Ac + ((wy * 2 + nt) * 2 + ks) * 512 + l16);
        }
#pragma unroll
        for (int ks = 0; ks < 2; ++ks)
#pragma unroll
            for (int mt = 0; mt < MT; ++mt)
#pragma unroll
                for (int nt = 0; nt < 2; ++nt)
                    acc[mt][nt] = __builtin_amdgcn_mfma_f32_32x32x16_bf16(fa[ks][mt], fb[ks][nt], acc[mt][nt], 0, 0, 0);
    }

    // ---- direct m-major panel writes (register-only, fully coalesced per instr)
    int bb2 = 2 * cb + wx;               // batch index (rows-per-batch = 32*MT)
#pragma unroll
    for (int mt = 0; mt < MT; ++mt) {
#pragma unroll
        for (int nt = 0; nt < 2; ++nt) {
            int mg = (n0 >> 5) + wy * 2 + nt;
            size_t pbase = ((size_t)(bb2 * 64 + mg) * MT + mt) * 1024;
#pragma unroll
            for (int eq = 0; eq < 4; ++eq) {
                size_t addr = pbase + (eq * 32 + ln) * 8 + 4 * hi;
                ushort4v pk;
                if (mode == 1) {
                    ushort4v sv = *(const ushort4v*)(Sub + addr);
#pragma unroll
                    for (int r = 0; r < 4; ++r)
                        pk[r] = f2bf(2.f * acc[mt][nt][eq * 4 + r] - bf2f(sv[r]));
                } else {
#pragma unroll
                    for (int r = 0; r < 4; ++r) pk[r] = f2bf(acc[mt][nt][eq * 4 + r]);
                }
                *(ushort4v*)(outM + addr) = pk;
            }
        }
    }

    // ---- optional [row][m]-panel output via LDS transpose (mode==0 callers only)
    if (outF) {
        __syncthreads();
#pragma unroll
        for (int p = 0; p < 2; ++p) {
            if (p) __syncthreads();
            if (wx == p) {
#pragma unroll
                for (int mt = 0; mt < MT; ++mt)
#pragma unroll
                    for (int nt = 0; nt < 2; ++nt)
#pragma unroll
                        for (int e = 0; e < 16; ++e) {
                            int cl = mt * 32 + 4 * hi + 8 * (e >> 2) + (e & 3);
                            int nl = wy * 64 + nt * 32 + ln;
                            SM[cl * 136 + nl] = f2bf(acc[mt][nt][e]);
                        }
            }
            __syncthreads();
#pragma unroll
            for (int pp = 0; pp < 2 * MT; ++pp) {
                int S = t + 256 * pp;
                int rgl = S >> 9, kgl = (S >> 7) & 3, sl = S & 127;
                int c = sl >> 5, r = sl & 31;
                short8 v = *(const short8*)(SM + (rgl * 32 + r) * 136 + kgl * 32 + c * 8);
                size_t gaddr = ((size_t)((c0 >> 5) + p * MT + rgl) * 64 + (n0 >> 5) + kgl) * 1024 + sl * 8;
                *(short8*)(outF + gaddr) = v;
            }
        }
    }
}

// ---------------------------------------------------------------- ru projection: panel-native GEMM 128m x 128o, K=384
// M-op: X{0,1,2}m panels. N-op: Wru panels. Fused sigmoid; outputs RH0f (u-major), RH0m (m-major), Ut bf16.
__global__ __launch_bounds__(256)
void k_proj_ru(const u16* __restrict__ X0m, const u16* __restrict__ X1m, const u16* __restrict__ X2m,
               const u16* __restrict__ Wp, const float* __restrict__ bias, const float* __restrict__ hx,
               u16* __restrict__ RH0f, u16* __restrict__ RH0m, u16* __restrict__ Ut) {
    __shared__ u16 SM[16384];            // X dbuf 2x4096 + W dbuf 2x4096
    u16 *Xa = SM, *Xb = SM + 4096, *Wa = SM + 8192, *Wb = SM + 12288;
    int mb = blockIdx.x, b = blockIdx.y;
    int m0 = mb * 128, mg0 = mb * 4;
    int t = threadIdx.x, wave = t >> 6, lane = t & 63;
    int wx = wave & 1, wyy = wave >> 1;
    int ln = lane & 31, hi = lane >> 5;
    const u16* Xs[3] = {X0m, X1m, X2m};
    int p0 = t >> 7, s0 = t & 127;

    float16v acc[2][2];
#pragma unroll
    for (int i = 0; i < 2; ++i)
#pragma unroll
        for (int j = 0; j < 2; ++j)
#pragma unroll
            for (int e = 0; e < 16; ++e) acc[i][j][e] = 0.f;

    gl2lds16(Xs[0] + ((size_t)((b * 64 + mg0 + p0) * 4)) * 1024 + s0 * 8, Xa + t * 8);
    gl2lds16(Xs[0] + ((size_t)((b * 64 + mg0 + p0 + 2) * 4)) * 1024 + s0 * 8, Xa + (t + 256) * 8);
    gl2lds16(Wp + ((size_t)(p0 * 12)) * 1024 + s0 * 8, Wa + t * 8);
    gl2lds16(Wp + ((size_t)((p0 + 2) * 12)) * 1024 + s0 * 8, Wa + (t + 256) * 8);

    for (int kq = 0; kq < 12; ++kq) {
        u16* Xc = (kq & 1) ? Xb : Xa;
        u16* Wc = (kq & 1) ? Wb : Wa;
        __syncthreads();
        if (kq + 1 < 12) {
            int k2 = kq + 1, kd = k2 >> 2, kg = k2 & 3;
            u16* Xn = (kq & 1) ? Xa : Xb;
            u16* Wn = (kq & 1) ? Wa : Wb;
            const u16* xb = Xs[kd];
            gl2lds16(xb + ((size_t)((b * 64 + mg0 + p0) * 4 + kg)) * 1024 + s0 * 8, Xn + t * 8);
            gl2lds16(xb + ((size_t)((b * 64 + mg0 + p0 + 2) * 4 + kg)) * 1024 + s0 * 8, Xn + (t + 256) * 8);
            gl2lds16(Wp + ((size_t)(p0 * 12 + k2)) * 1024 + s0 * 8, Wn + t * 8);
            gl2lds16(Wp + ((size_t)((p0 + 2) * 12 + k2)) * 1024 + s0 * 8, Wn + (t + 256) * 8);
        }
        short8 fa[2][2], fb[2][2];
#pragma unroll
        for (int ks = 0; ks < 2; ++ks) {
#pragma unroll
            for (int mt = 0; mt < 2; ++mt)
                fa[ks][mt] = *(const short8*)(Xc + ((wx * 2 + mt) * 2 + ks) * 512 + lane * 8);
#pragma unroll
            for (int nt = 0; nt < 2; ++nt)
                fb[ks][nt] = *(const short8*)(Wc + ((wyy * 2 + nt) * 2 + ks) * 512 + lane * 8);
        }
#pragma unroll
        for (int ks = 0; ks < 2; ++ks)
#pragma unroll
            for (int mt = 0; mt < 2; ++mt)
#pragma unroll
                for (int nt = 0; nt < 2; ++nt)
                    acc[mt][nt] = __builtin_amdgcn_mfma_f32_32x32x16_bf16(fa[ks][mt], fb[ks][nt], acc[mt][nt], 0, 0, 0);
    }
    __syncthreads();                     // K-loop LDS reads done; SM reusable as [m128][76]
    if (wyy == 0) {
        // r-gate: rh = sigmoid(acc+b)*h -> RH0f direct + SM for RH0m
#pragma unroll
        for (int mt = 0; mt < 2; ++mt)
#pragma unroll
            for (int nt = 0; nt < 2; ++nt) {
                int o = nt * 32 + ln;
                float bo = bias[o];
                u16 vals[16];
#pragma unroll
                for (int e = 0; e < 16; ++e) {
                    int ml = wx * 64 + mt * 32 + 4 * hi + 8 * (e >> 2) + (e & 3);
                    float sg = sigmoidf_(acc[mt][nt][e] + bo);
                    float hh = hx[((size_t)b * NN + m0 + ml) * 64 + o];
                    vals[e] = f2bf(sg * hh);
                    SM[ml * 76 + o] = vals[e];
                }
#pragma unroll
                for (int eq = 0; eq < 4; ++eq) {
                    ushort4v pk;
#pragma unroll
                    for (int r = 0; r < 4; ++r) pk[r] = vals[eq * 4 + r];
                    size_t addr = ((size_t)(b * 2 + nt) * 64 + mg0 + wx * 2 + mt) * 1024 + (eq * 32 + ln) * 8 + 4 * hi;
                    *(ushort4v*)(RH0f + addr) = pk;
                }
            }
    } else {
        // u-gate -> Ut bf16 row-major
#pragma unroll
        for (int mt = 0; mt < 2; ++mt)
#pragma unroll
            for (int nt = 0; nt < 2; ++nt) {
                int og = nt * 32 + ln;
                float bo = bias[64 + og];
#pragma unroll
                for (int e = 0; e < 16; ++e) {
                    int ml = wx * 64 + mt * 32 + 4 * hi + 8 * (e >> 2) + (e & 3);
                    Ut[((size_t)b * NN + m0 + ml) * 64 + og] = f2bf(sigmoidf_(acc[mt][nt][e] + bo));
                }
            }
    }
    __syncthreads();
    // SM[m][76] -> RH0m panels (8 panels: 4 mg x 2 ug)
#pragma unroll
    for (int j = 0; j < 4; ++j) {
        int C = t + 256 * j;
        int p = C >> 7, sl = C & 127;
        int mgl = p >> 1, ug = p & 1;
        int cq = sl >> 5, r = sl & 31;
        short8 v = *(const short8*)(SM + (mgl * 32 + r) * 76 + ug * 32 + cq * 8);
        *(short8*)(RH0m + ((size_t)((b * 64 + mg0 + mgl) * 2 + ug)) * 1024 + sl * 8) = v;
    }
}

// ---------------------------------------------------------------- c projection: 128m x 64o, K=384 (X + RH), fused tanh + combine
__global__ __launch_bounds__(256)
void k_proj_c(const u16* __restrict__ X0m, const u16* __restrict__ X1m, const u16* __restrict__ X2m,
              const u16* __restrict__ RH0m, const u16* __restrict__ RH1m, const u16* __restrict__ RH2m,
              const u16* __restrict__ Wp, const float* __restrict__ bias,
              const float* __restrict__ hx, const u16* __restrict__ Ut,
              float* __restrict__ out) {
    __shared__ u16 SM[12288];            // X dbuf 2x4096 + W dbuf 2x2048
    u16 *Xa = SM, *Xb = SM + 4096, *Wa = SM + 8192, *Wb = SM + 10240;
    int mb = blockIdx.x, b = blockIdx.y;
    int m0 = mb * 128, mg0 = mb * 4;
    int t = threadIdx.x, wave = t >> 6, lane = t & 63;
    int wx = wave & 1, wyy = wave >> 1;
    int ln = lane & 31, hi = lane >> 5;
    const u16* Xs[3] = {X0m, X1m, X2m};
    const u16* Rs[3] = {RH0m, RH1m, RH2m};
    int p0 = t >> 7, s0 = t & 127;

    float16v acc[2];
#pragma unroll
    for (int i = 0; i < 2; ++i)
#pragma unroll
        for (int e = 0; e < 16; ++e) acc[i][e] = 0.f;

    // kq=0: X0, kg=0
    gl2lds16(Xs[0] + ((size_t)((b * 64 + mg0 + p0) * 4)) * 1024 + s0 * 8, Xa + t * 8);
    gl2lds16(Xs[0] + ((size_t)((b * 64 + mg0 + p0 + 2) * 4)) * 1024 + s0 * 8, Xa + (t + 256) * 8);
    gl2lds16(Wp + ((size_t)(p0 * 12)) * 1024 + s0 * 8, Wa + t * 8);   // p0 in 0..1 covers both o-panels

    for (int kq = 0; kq < 12; ++kq) {
        u16* Xc = (kq & 1) ? Xb : Xa;
        u16* Wc = (kq & 1) ? Wb : Wa;
        __syncthreads();
        if (kq + 1 < 12) {
            int k2 = kq + 1, kd = k2 >> 2, fb2 = (k2 & 3) * 32;
            u16* Xn = (kq & 1) ? Xa : Xb;
            u16* Wn = (kq & 1) ? Wa : Wb;
            const u16* mat; size_t pb0, pb1;
            if (fb2 < 64) {
                mat = Xs[kd];
                pb0 = ((size_t)((b * 64 + mg0 + p0) * 4 + (fb2 >> 5))) * 1024;
                pb1 = ((size_t)((b * 64 + mg0 + p0 + 2) * 4 + (fb2 >> 5))) * 1024;
            } else {
                mat = Rs[kd];
                pb0 = ((size_t)((b * 64 + mg0 + p0) * 2 + ((fb2 >> 5) - 2))) * 1024;
                pb1 = ((size_t)((b * 64 + mg0 + p0 + 2) * 2 + ((fb2 >> 5) - 2))) * 1024;
            }
            gl2lds16(mat + pb0 + s0 * 8, Xn + t * 8);
            gl2lds16(mat + pb1 + s0 * 8, Xn + (t + 256) * 8);
            gl2lds16(Wp + ((size_t)(p0 * 12 + k2)) * 1024 + s0 * 8, Wn + t * 8);
        }
        short8 fa[2][2], fbg[2];
#pragma unroll
        for (int ks = 0; ks < 2; ++ks) {
#pragma unroll
            for (int mt = 0; mt < 2; ++mt)
                fa[ks][mt] = *(const short8*)(Xc + ((wx * 2 + mt) * 2 + ks) * 512 + lane * 8);
            fbg[ks] = *(const short8*)(Wc + (wyy * 2 + ks) * 512 + lane * 8);
        }
#pragma unroll
        for (int ks = 0; ks < 2; ++ks)
#pragma unroll
            for (int mt = 0; mt < 2; ++mt)
                acc[mt] = __builtin_amdgcn_mfma_f32_32x32x16_bf16(fa[ks][mt], fbg[ks], acc[mt], 0, 0, 0);
    }
    int o = wyy * 32 + ln;
    float bo = bias[o];
#pragma unroll
    for (int mt = 0; mt < 2; ++mt)
#pragma unroll
        for (int e = 0; e < 16; ++e) {
            int ml = wx * 64 + mt * 32 + 4 * hi + 8 * (e >> 2) + (e & 3);
            size_t idx = ((size_t)b * NN + m0 + ml) * 64 + o;
            float c = tanhf(acc[mt][e] + bo);
            float u = bf2f(Ut[idx]);
            float hh = hx[idx];
            out[idx] = u * hh + (1.0f - u) * c;
        }
}

// ---------------------------------------------------------------- launch
extern "C" void kernel_launch(void* const* d_in, const int* in_sizes, int n_in,
                              void* d_out, int out_size, void* d_ws, size_t ws_size,
                              hipStream_t stream) {
    const float* x    = (const float*)d_in[0];
    const float* hx   = (const float*)d_in[1];
    const float* adj  = (const float*)d_in[2];
    const float* W_ru = (const float*)d_in[3];
    const float* b_ru = (const float*)d_in[4];
    const float* W_c  = (const float*)d_in[5];
    const float* b_c  = (const float*)d_in[6];
    float* out = (float*)d_out;

    char* ws = (char*)d_ws;
    size_t off = 0;
    auto alloc = [&](size_t bytes) -> void* {
        void* p = ws + off;
        off += (bytes + 255) & ~(size_t)255;
        return p;
    };
    float* d_inv = (float*)alloc((size_t)NN * 4);
    u16* adjT = (u16*)alloc((size_t)NN * NN * 2);
    u16* Wru  = (u16*)alloc((size_t)FD * KT * 2);
    u16* Wc   = (u16*)alloc((size_t)UD * KT * 2);
    u16* X0f = (u16*)alloc((size_t)NB * FD * NN * 2);   // aliased by RH0f after gemm#1
    u16* X1f = (u16*)alloc((size_t)NB * FD * NN * 2);   // aliased by RH1f after gemm#2
    u16* X0m = (u16*)alloc((size_t)NB * FD * NN * 2);
    u16* X1m = (u16*)alloc((size_t)NB * FD * NN * 2);
    u16* X2m = (u16*)alloc((size_t)NB * FD * NN * 2);
    u16* RH0m = (u16*)alloc((size_t)NB * UD * NN * 2);
    u16* RH1m = (u16*)alloc((size_t)NB * UD * NN * 2);
    u16* RH2m = (u16*)alloc((size_t)NB * UD * NN * 2);
    u16* Ut   = (u16*)alloc((size_t)NB * UD * NN * 2);
    u16* RH0f = X0f;
    u16* RH1f = X1f;

    k_rownorm<<<dim3(NN), dim3(256), 0, stream>>>(adj, d_inv);
    k_adjT<<<dim3(32, 32), dim3(256), 0, stream>>>(adj, d_inv, adjT);
    k_reorderW<<<dim3((KT * FD + 255) / 256), dim3(256), 0, stream>>>(W_ru, Wru, FD);
    k_reorderW<<<dim3((KT * UD + 255) / 256), dim3(256), 0, stream>>>(W_c, Wc, UD);
    k_xcat<<<dim3(16, NB), dim3(256), 0, stream>>>(x, hx, X0f, X0m);
    // X1 = A@X0 (dual out); X2 = 2A@X1 - X0 (m-major only)
    k_gemm<4><<<dim3(32, 16), dim3(256), 0, stream>>>(adjT, X0f, X1f, X1m, nullptr, 0, 32);
    k_gemm<4><<<dim3(32, 16), dim3(256), 0, stream>>>(adjT, X1f, nullptr, X2m, X0m, 1, 32);
    k_proj_ru<<<dim3(16, NB), dim3(256), 0, stream>>>(X0m, X1m, X2m, Wru, b_ru, hx, RH0f, RH0m, Ut);
    // RH1 = A@RH0 (dual); RH2 = 2A@RH1 - RH0 (m-major only)
    k_gemm<2><<<dim3(32, 16), dim3(256), 0, stream>>>(adjT, RH0f, RH1f, RH1m, nullptr, 0, 32);
    k_gemm<2><<<dim3(32, 16), dim3(256), 0, stream>>>(adjT, RH1f, nullptr, RH2m, RH0m, 1, 32);
    k_proj_c<<<dim3(16, NB), dim3(256), 0, stream>>>(X0m, X1m, X2m, RH0m, RH1m, RH2m, Wc, b_c, hx, Ut, out);
}

// Round 8
// 444.789 us; speedup vs baseline: 1.1692x; 1.1692x over previous
//
#include <hip/hip_runtime.h>
#include <math.h>

typedef __attribute__((ext_vector_type(8))) short short8;
typedef __attribute__((ext_vector_type(4))) float float4v;
typedef __attribute__((ext_vector_type(16))) float float16v;
typedef __attribute__((ext_vector_type(4))) unsigned short ushort4v;
typedef unsigned short u16;
typedef unsigned int u32;

#define NB 64
#define NN 2048
#define FD 128
#define UD 64
#define KT 384

// ---- PANEL FORMAT ----
// matrix[row][k] -> flat[(rowgrp*KGRPS + kgrp)*1024 + (((k>>3)&3)*32 + (row&31))*8 + (k&7)]
// 32x32 panel = 2KB contiguous; slot order == MFMA fragment order (lane=row, 16B/lane).
// Chebyshev fold: proj uses W0'=W0-W2, W1, W2'=2*W2 so only Y=A@X1 (not X2) is needed.

__device__ __forceinline__ u16 f2bf(float f) {
    unsigned int u = __float_as_uint(f);
    u += 0x7fffu + ((u >> 16) & 1u);
    return (u16)(u >> 16);
}
__device__ __forceinline__ float bf2f(u16 s) {
    return __uint_as_float(((unsigned int)s) << 16);
}
__device__ __forceinline__ float sigmoidf_(float x) {
    return 1.0f / (1.0f + expf(-x));
}
__device__ __forceinline__ void gl2lds16(const u16* g, u16* l) {
    __builtin_amdgcn_global_load_lds((const __attribute__((address_space(1))) unsigned int*)g,
                                     (__attribute__((address_space(3))) unsigned int*)l,
                                     16, 0, 0);
}

// ---------------------------------------------------------------- rownorm
__global__ void k_rownorm(const float* __restrict__ adj, float* __restrict__ d_inv) {
    int m = blockIdx.x;
    const float4v* row = (const float4v*)(adj + (size_t)m * NN);
    float s = 0.f;
    for (int i = threadIdx.x; i < NN / 4; i += 256) {
        float4v v = row[i];
        s += v.x + v.y + v.z + v.w;
    }
    __shared__ float red[4];
    for (int off = 32; off; off >>= 1) s += __shfl_down(s, off, 64);
    if ((threadIdx.x & 63) == 0) red[threadIdx.x >> 6] = s;
    __syncthreads();
    if (threadIdx.x == 0) {
        float t = red[0] + red[1] + red[2] + red[3] + 1.0f;
        d_inv[m] = 1.0f / t;
    }
}

// ---------------------------------------------------------------- adjT panels (rows n, k=m)
__global__ void k_adjT(const float* __restrict__ adj, const float* __restrict__ d_inv,
                       u16* __restrict__ adjT) {
    __shared__ u16 T[64 * 72];
    int m0 = blockIdx.x * 64;
    int n0 = blockIdx.y * 64;
    int t = threadIdx.x;
    for (int p = 0; p < 4; ++p) {
        int idx = t + 256 * p;
        int i  = idx >> 4;
        int n4 = idx & 15;
        int m = m0 + i;
        float4v v = *(const float4v*)(adj + (size_t)m * NN + n0 + n4 * 4);
        float di = d_inv[m];
        float vv[4] = {v.x, v.y, v.z, v.w};
#pragma unroll
        for (int j = 0; j < 4; ++j) {
            int n = n0 + n4 * 4 + j;
            float a = vv[j] + ((m == n) ? 1.0f : 0.0f);
            T[(n4 * 4 + j) * 72 + i] = f2bf(a * di);
        }
    }
    __syncthreads();
#pragma unroll
    for (int p = 0; p < 2; ++p) {
        int S = t + 256 * p;
        int rgl = S >> 8, kgl = (S >> 7) & 1, s = S & 127;
        int c = s >> 5, r = s & 31;
        short8 v = *(const short8*)(T + (rgl * 32 + r) * 72 + kgl * 32 + c * 8);
        *(short8*)(adjT + ((size_t)((n0 >> 5) + rgl) * 64 + (m0 >> 5) + kgl) * 1024 + s * 8) = v;
    }
}

// ---------------------------------------------------------------- W -> panels, with Chebyshev fold
// kd=0: W0-W2 ; kd=1: W1 ; kd=2: 2*W2
__global__ void k_reorderW(const float* __restrict__ W, u16* __restrict__ Wt, int OD) {
    int idx = blockIdx.x * 256 + threadIdx.x;
    if (idx >= KT * OD) return;
    int o  = idx % OD;
    int kp = idx / OD;
    int kd = kp >> 7, f = kp & 127;
    float v;
    if (kd == 0)      v = W[(size_t)(f * 3 + 0) * OD + o] - W[(size_t)(f * 3 + 2) * OD + o];
    else if (kd == 1) v = W[(size_t)(f * 3 + 1) * OD + o];
    else              v = 2.0f * W[(size_t)(f * 3 + 2) * OD + o];
    size_t dst = ((size_t)(o >> 5) * 12 + (kp >> 5)) * 1024 + (((kp >> 3) & 3) * 32 + (o & 31)) * 8 + (kp & 7);
    Wt[dst] = f2bf(v);
}

// ---------------------------------------------------------------- xcat: X0f panels + X0m panels
__global__ void k_xcat(const float* __restrict__ x, const float* __restrict__ h,
                       u16* __restrict__ X0f, u16* __restrict__ X0m) {
    __shared__ u16 T[128 * 136];
    int m0 = blockIdx.x * 128;
    int b  = blockIdx.y;
    int t = threadIdx.x;
    const float* srcs[2] = { x + (size_t)b * (NN * 64), h + (size_t)b * (NN * 64) };
    for (int s = 0; s < 2; ++s) {
        const float* src = srcs[s];
        for (int p = 0; p < 8; ++p) {
            int idx = t + 256 * p;
            int mi = idx >> 4;
            int f4 = idx & 15;
            float4v v = *(const float4v*)(src + (size_t)(m0 + mi) * 64 + f4 * 4);
            float vv[4] = {v.x, v.y, v.z, v.w};
#pragma unroll
            for (int j = 0; j < 4; ++j)
                T[(s * 64 + f4 * 4 + j) * 136 + mi] = f2bf(vv[j]);
        }
    }
    __syncthreads();
#pragma unroll
    for (int p = 0; p < 8; ++p) {
        int S = t + 256 * p;
        int fgl = S >> 9, kgl = (S >> 7) & 3, s = S & 127;
        int c = s >> 5, r = s & 31;
        short8 v = *(const short8*)(T + (fgl * 32 + r) * 136 + kgl * 32 + c * 8);
        *(short8*)(X0f + ((size_t)(b * 4 + fgl) * 64 + (m0 >> 5) + kgl) * 1024 + s * 8) = v;
    }
#pragma unroll
    for (int p = 0; p < 8; ++p) {
        int S = t + 256 * p;
        int fc = S >> 7;
        int mi = S & 127;
        short8 v;
#pragma unroll
        for (int e = 0; e < 8; ++e) v[e] = (short)T[(fc * 8 + e) * 136 + mi];
        size_t dst = ((size_t)(b * 64 + (m0 >> 5) + (mi >> 5)) * 4 + (fc >> 2)) * 1024
                     + ((fc & 3) * 32 + (mi & 31)) * 8;
        *(short8*)(X0m + dst) = v;
    }
}

// ---------------------------------------------------------------- GEMM, 128x128 tile, 32x32x16 MFMA, 4 blocks/CU
// A: adjT (N-op). Bc: f-major panels (M-op). Out = A@Bc.
// outM: m-major panels. FG=4: batch=cb (X path, 128 f/batch); FG=2: batch=2cb+wx (RH path, 64 u/batch).
// outF (optional): f-major panels via LDS transpose.
template<int FG>
__global__ __launch_bounds__(256, 4)
void k_gemm(const u16* __restrict__ A, const u16* __restrict__ Bc,
            u16* __restrict__ outF, u16* __restrict__ outM, int cBlocks) {
    __shared__ u16 SM[16384];            // A dbuf 2x4096 + B dbuf 2x4096 (u16) = 32 KB
    u16* A0 = SM;            u16* A1 = SM + 4096;
    u16* B0 = SM + 8192;     u16* B1 = SM + 12288;

    int id = blockIdx.x + cBlocks * blockIdx.y;
    int band = cBlocks >> 3;
    int g = id & 7, s = id >> 3;
    int cb = g * band + (s % band);
    int nb = s / band;
    int c0 = cb * 128;
    int n0 = nb * 128;

    int t = threadIdx.x;
    int wave = t >> 6, lane = t & 63;
    int wy = wave & 1, wx = wave >> 1;
    int ln = lane & 31, hi = lane >> 5;
    int l16 = lane * 8;

    const u16* gaP[2];
    const u16* gbP[2];
#pragma unroll
    for (int i = 0; i < 2; ++i) {
        int T = t + 256 * i;
        gaP[i] = A  + ((size_t)((n0 >> 5) + (T >> 7)) * 64) * 1024 + (size_t)(T & 127) * 8;
        gbP[i] = Bc + ((size_t)((c0 >> 5) + (T >> 7)) * 64) * 1024 + (size_t)(T & 127) * 8;
    }

    float16v acc[2][2];
#pragma unroll
    for (int i = 0; i < 2; ++i)
#pragma unroll
        for (int j = 0; j < 2; ++j)
#pragma unroll
            for (int e = 0; e < 16; ++e) acc[i][j][e] = 0.f;

#pragma unroll
    for (int i = 0; i < 2; ++i) { gl2lds16(gaP[i], A0 + (t + 256 * i) * 8); gl2lds16(gbP[i], B0 + (t + 256 * i) * 8); }

#pragma unroll 2
    for (int it = 0; it < 64; ++it) {
        u16* Ac = (it & 1) ? A1 : A0;
        u16* Bs = (it & 1) ? B1 : B0;
        __syncthreads();
        if (it + 1 < 64) {
            int ko = (it + 1) * 1024;
            u16* An = (it & 1) ? A0 : A1;
            u16* Bn = (it & 1) ? B0 : B1;
#pragma unroll
            for (int i = 0; i < 2; ++i) { gl2lds16(gaP[i] + ko, An + (t + 256 * i) * 8); gl2lds16(gbP[i] + ko, Bn + (t + 256 * i) * 8); }
        }
        short8 fa[2][2], fb[2][2];
#pragma unroll
        for (int ks = 0; ks < 2; ++ks) {
#pragma unroll
            for (int mt = 0; mt < 2; ++mt)
                fa[ks][mt] = *(const short8*)(Bs + ((wx * 2 + mt) * 2 + ks) * 512 + l16);
#pragma unroll
            for (int nt = 0; nt < 2; ++nt)
                fb[ks][nt] = *(const short8*)(Ac + ((wy * 2 + nt) * 2 + ks) * 512 + l16);
        }
#pragma unroll
        for (int ks = 0; ks < 2; ++ks)
#pragma unroll
            for (int mt = 0; mt < 2; ++mt)
#pragma unroll
                for (int nt = 0; nt < 2; ++nt)
                    acc[mt][nt] = __builtin_amdgcn_mfma_f32_32x32x16_bf16(fa[ks][mt], fb[ks][nt], acc[mt][nt], 0, 0, 0);
    }

    // ---- m-major direct panel writes (coalesced 512B per (mt,nt,eq))
#pragma unroll
    for (int mt = 0; mt < 2; ++mt) {
#pragma unroll
        for (int nt = 0; nt < 2; ++nt) {
            int mg = (n0 >> 5) + wy * 2 + nt;
            int batch = (FG == 4) ? cb : (2 * cb + wx);
            int fg = (FG == 4) ? (wx * 2 + mt) : mt;
            size_t pbase = ((size_t)(batch * 64 + mg) * FG + fg) * 1024;
#pragma unroll
            for (int eq = 0; eq < 4; ++eq) {
                ushort4v pk;
#pragma unroll
                for (int r = 0; r < 4; ++r) pk[r] = f2bf(acc[mt][nt][eq * 4 + r]);
                *(ushort4v*)(outM + pbase + (eq * 32 + ln) * 8 + 4 * hi) = pk;
            }
        }
    }

    // ---- optional f-major panels via LDS transpose (64 c-rows per pass)
    if (outF) {
        __syncthreads();
#pragma unroll
        for (int p = 0; p < 2; ++p) {
            if (p) __syncthreads();
            if (wx == p) {
#pragma unroll
                for (int mt = 0; mt < 2; ++mt)
#pragma unroll
                    for (int nt = 0; nt < 2; ++nt)
#pragma unroll
                        for (int e = 0; e < 16; ++e) {
                            int cl = mt * 32 + 4 * hi + 8 * (e >> 2) + (e & 3);
                            int nl = wy * 64 + nt * 32 + ln;
                            SM[cl * 136 + nl] = f2bf(acc[mt][nt][e]);
                        }
            }
            __syncthreads();
#pragma unroll
            for (int pp = 0; pp < 4; ++pp) {
                int S = t + 256 * pp;
                int rgl = S >> 9, kgl = (S >> 7) & 3, sl = S & 127;
                int c = sl >> 5, r = sl & 31;
                short8 v = *(const short8*)(SM + (rgl * 32 + r) * 136 + kgl * 32 + c * 8);
                size_t gaddr = ((size_t)((c0 >> 5) + p * 2 + rgl) * 64 + (n0 >> 5) + kgl) * 1024 + sl * 8;
                *(short8*)(outF + gaddr) = v;
            }
        }
    }
}

// ---------------------------------------------------------------- ru projection: 128m x 128o, K=384, fused sigmoid
__global__ __launch_bounds__(256)
void k_proj_ru(const u16* __restrict__ X0m, const u16* __restrict__ X1m, const u16* __restrict__ Ym,
               const u16* __restrict__ Wp, const float* __restrict__ bias, const float* __restrict__ hx,
               u16* __restrict__ RH0f, u16* __restrict__ RH0m, u16* __restrict__ Ut) {
    __shared__ u16 SM[16384];
    u16 *Xa = SM, *Xb = SM + 4096, *Wa = SM + 8192, *Wb = SM + 12288;
    int mb = blockIdx.x, b = blockIdx.y;
    int m0 = mb * 128, mg0 = mb * 4;
    int t = threadIdx.x, wave = t >> 6, lane = t & 63;
    int wx = wave & 1, wyy = wave >> 1;
    int ln = lane & 31, hi = lane >> 5;
    const u16* Xs[3] = {X0m, X1m, Ym};
    int p0 = t >> 7, s0 = t & 127;

    float16v acc[2][2];
#pragma unroll
    for (int i = 0; i < 2; ++i)
#pragma unroll
        for (int j = 0; j < 2; ++j)
#pragma unroll
            for (int e = 0; e < 16; ++e) acc[i][j][e] = 0.f;

    gl2lds16(Xs[0] + ((size_t)((b * 64 + mg0 + p0) * 4)) * 1024 + s0 * 8, Xa + t * 8);
    gl2lds16(Xs[0] + ((size_t)((b * 64 + mg0 + p0 + 2) * 4)) * 1024 + s0 * 8, Xa + (t + 256) * 8);
    gl2lds16(Wp + ((size_t)(p0 * 12)) * 1024 + s0 * 8, Wa + t * 8);
    gl2lds16(Wp + ((size_t)((p0 + 2) * 12)) * 1024 + s0 * 8, Wa + (t + 256) * 8);

    for (int kq = 0; kq < 12; ++kq) {
        u16* Xc = (kq & 1) ? Xb : Xa;
        u16* Wc = (kq & 1) ? Wb : Wa;
        __syncthreads();
        if (kq + 1 < 12) {
            int k2 = kq + 1, kd = k2 >> 2, kg = k2 & 3;
            u16* Xn = (kq & 1) ? Xa : Xb;
            u16* Wn = (kq & 1) ? Wa : Wb;
            const u16* xb = Xs[kd];
            gl2lds16(xb + ((size_t)((b * 64 + mg0 + p0) * 4 + kg)) * 1024 + s0 * 8, Xn + t * 8);
            gl2lds16(xb + ((size_t)((b * 64 + mg0 + p0 + 2) * 4 + kg)) * 1024 + s0 * 8, Xn + (t + 256) * 8);
            gl2lds16(Wp + ((size_t)(p0 * 12 + k2)) * 1024 + s0 * 8, Wn + t * 8);
            gl2lds16(Wp + ((size_t)((p0 + 2) * 12 + k2)) * 1024 + s0 * 8, Wn + (t + 256) * 8);
        }
        short8 fa[2][2], fb[2][2];
#pragma unroll
        for (int ks = 0; ks < 2; ++ks) {
#pragma unroll
            for (int mt = 0; mt < 2; ++mt)
                fa[ks][mt] = *(const short8*)(Xc + ((wx * 2 + mt) * 2 + ks) * 512 + lane * 8);
#pragma unroll
            for (int nt = 0; nt < 2; ++nt)
                fb[ks][nt] = *(const short8*)(Wc + ((wyy * 2 + nt) * 2 + ks) * 512 + lane * 8);
        }
#pragma unroll
        for (int ks = 0; ks < 2; ++ks)
#pragma unroll
            for (int mt = 0; mt < 2; ++mt)
#pragma unroll
                for (int nt = 0; nt < 2; ++nt)
                    acc[mt][nt] = __builtin_amdgcn_mfma_f32_32x32x16_bf16(fa[ks][mt], fb[ks][nt], acc[mt][nt], 0, 0, 0);
    }
    __syncthreads();
    if (wyy == 0) {
#pragma unroll
        for (int mt = 0; mt < 2; ++mt)
#pragma unroll
            for (int nt = 0; nt < 2; ++nt) {
                int o = nt * 32 + ln;
                float bo = bias[o];
                u16 vals[16];
#pragma unroll
                for (int e = 0; e < 16; ++e) {
                    int ml = wx * 64 + mt * 32 + 4 * hi + 8 * (e >> 2) + (e & 3);
                    float sg = sigmoidf_(acc[mt][nt][e] + bo);
                    float hh = hx[((size_t)b * NN + m0 + ml) * 64 + o];
                    vals[e] = f2bf(sg * hh);
                    SM[ml * 76 + o] = vals[e];
                }
#pragma unroll
                for (int eq = 0; eq < 4; ++eq) {
                    ushort4v pk;
#pragma unroll
                    for (int r = 0; r < 4; ++r) pk[r] = vals[eq * 4 + r];
                    size_t addr = ((size_t)(b * 2 + nt) * 64 + mg0 + wx * 2 + mt) * 1024 + (eq * 32 + ln) * 8 + 4 * hi;
                    *(ushort4v*)(RH0f + addr) = pk;
                }
            }
    } else {
#pragma unroll
        for (int mt = 0; mt < 2; ++mt)
#pragma unroll
            for (int nt = 0; nt < 2; ++nt) {
                int og = nt * 32 + ln;
                float bo = bias[64 + og];
#pragma unroll
                for (int e = 0; e < 16; ++e) {
                    int ml = wx * 64 + mt * 32 + 4 * hi + 8 * (e >> 2) + (e & 3);
                    Ut[((size_t)b * NN + m0 + ml) * 64 + og] = f2bf(sigmoidf_(acc[mt][nt][e] + bo));
                }
            }
    }
    __syncthreads();
#pragma unroll
    for (int j = 0; j < 4; ++j) {
        int C = t + 256 * j;
        int p = C >> 7, sl = C & 127;
        int mgl = p >> 1, ug = p & 1;
        int cq = sl >> 5, r = sl & 31;
        short8 v = *(const short8*)(SM + (mgl * 32 + r) * 76 + ug * 32 + cq * 8);
        *(short8*)(RH0m + ((size_t)((b * 64 + mg0 + mgl) * 2 + ug)) * 1024 + sl * 8) = v;
    }
}

// ---------------------------------------------------------------- c projection: 128m x 64o, K=384, fused tanh + combine
__global__ __launch_bounds__(256)
void k_proj_c(const u16* __restrict__ X0m, const u16* __restrict__ X1m, const u16* __restrict__ Ym,
              const u16* __restrict__ RH0m, const u16* __restrict__ RH1m, const u16* __restrict__ Zm,
              const u16* __restrict__ Wp, const float* __restrict__ bias,
              const float* __restrict__ hx, const u16* __restrict__ Ut,
              float* __restrict__ out) {
    __shared__ u16 SM[12288];
    u16 *Xa = SM, *Xb = SM + 4096, *Wa = SM + 8192, *Wb = SM + 10240;
    int mb = blockIdx.x, b = blockIdx.y;
    int m0 = mb * 128, mg0 = mb * 4;
    int t = threadIdx.x, wave = t >> 6, lane = t & 63;
    int wx = wave & 1, wyy = wave >> 1;
    int ln = lane & 31, hi = lane >> 5;
    const u16* Xs[3] = {X0m, X1m, Ym};
    const u16* Rs[3] = {RH0m, RH1m, Zm};
    int p0 = t >> 7, s0 = t & 127;

    float16v acc[2];
#pragma unroll
    for (int i = 0; i < 2; ++i)
#pragma unroll
        for (int e = 0; e < 16; ++e) acc[i][e] = 0.f;

    gl2lds16(Xs[0] + ((size_t)((b * 64 + mg0 + p0) * 4)) * 1024 + s0 * 8, Xa + t * 8);
    gl2lds16(Xs[0] + ((size_t)((b * 64 + mg0 + p0 + 2) * 4)) * 1024 + s0 * 8, Xa + (t + 256) * 8);
    gl2lds16(Wp + ((size_t)(p0 * 12)) * 1024 + s0 * 8, Wa + t * 8);

    for (int kq = 0; kq < 12; ++kq) {
        u16* Xc = (kq & 1) ? Xb : Xa;
        u16* Wc = (kq & 1) ? Wb : Wa;
        __syncthreads();
        if (kq + 1 < 12) {
            int k2 = kq + 1, kd = k2 >> 2, fb2 = (k2 & 3) * 32;
            u16* Xn = (kq & 1) ? Xa : Xb;
            u16* Wn = (kq & 1) ? Wa : Wb;
            const u16* mat; size_t pb0, pb1;
            if (fb2 < 64) {
                mat = Xs[kd];
                pb0 = ((size_t)((b * 64 + mg0 + p0) * 4 + (fb2 >> 5))) * 1024;
                pb1 = ((size_t)((b * 64 + mg0 + p0 + 2) * 4 + (fb2 >> 5))) * 1024;
            } else {
                mat = Rs[kd];
                pb0 = ((size_t)((b * 64 + mg0 + p0) * 2 + ((fb2 >> 5) - 2))) * 1024;
                pb1 = ((size_t)((b * 64 + mg0 + p0 + 2) * 2 + ((fb2 >> 5) - 2))) * 1024;
            }
            gl2lds16(mat + pb0 + s0 * 8, Xn + t * 8);
            gl2lds16(mat + pb1 + s0 * 8, Xn + (t + 256) * 8);
            gl2lds16(Wp + ((size_t)(p0 * 12 + k2)) * 1024 + s0 * 8, Wn + t * 8);
        }
        short8 fa[2][2], fbg[2];
#pragma unroll
        for (int ks = 0; ks < 2; ++ks) {
#pragma unroll
            for (int mt = 0; mt < 2; ++mt)
                fa[ks][mt] = *(const short8*)(Xc + ((wx * 2 + mt) * 2 + ks) * 512 + lane * 8);
            fbg[ks] = *(const short8*)(Wc + (wyy * 2 + ks) * 512 + lane * 8);
        }
#pragma unroll
        for (int ks = 0; ks < 2; ++ks)
#pragma unroll
            for (int mt = 0; mt < 2; ++mt)
                acc[mt] = __builtin_amdgcn_mfma_f32_32x32x16_bf16(fa[ks][mt], fbg[ks], acc[mt], 0, 0, 0);
    }
    int o = wyy * 32 + ln;
    float bo = bias[o];
#pragma unroll
    for (int mt = 0; mt < 2; ++mt)
#pragma unroll
        for (int e = 0; e < 16; ++e) {
            int ml = wx * 64 + mt * 32 + 4 * hi + 8 * (e >> 2) + (e & 3);
            size_t idx = ((size_t)b * NN + m0 + ml) * 64 + o;
            float c = tanhf(acc[mt][e] + bo);
            float u = bf2f(Ut[idx]);
            float hh = hx[idx];
            out[idx] = u * hh + (1.0f - u) * c;
        }
}

// ---------------------------------------------------------------- launch
extern "C" void kernel_launch(void* const* d_in, const int* in_sizes, int n_in,
                              void* d_out, int out_size, void* d_ws, size_t ws_size,
                              hipStream_t stream) {
    const float* x    = (const float*)d_in[0];
    const float* hx   = (const float*)d_in[1];
    const float* adj  = (const float*)d_in[2];
    const float* W_ru = (const float*)d_in[3];
    const float* b_ru = (const float*)d_in[4];
    const float* W_c  = (const float*)d_in[5];
    const float* b_c  = (const float*)d_in[6];
    float* out = (float*)d_out;

    char* ws = (char*)d_ws;
    size_t off = 0;
    auto alloc = [&](size_t bytes) -> void* {
        void* p = ws + off;
        off += (bytes + 255) & ~(size_t)255;
        return p;
    };
    float* d_inv = (float*)alloc((size_t)NN * 4);
    u16* adjT = (u16*)alloc((size_t)NN * NN * 2);
    u16* Wru  = (u16*)alloc((size_t)FD * KT * 2);
    u16* Wc   = (u16*)alloc((size_t)UD * KT * 2);
    u16* X0f = (u16*)alloc((size_t)NB * FD * NN * 2);   // aliased as RH0f after gemm#1
    u16* X1f = (u16*)alloc((size_t)NB * FD * NN * 2);   // aliased as RH1f after gemm#2
    u16* X0m = (u16*)alloc((size_t)NB * FD * NN * 2);
    u16* X1m = (u16*)alloc((size_t)NB * FD * NN * 2);
    u16* Ym  = (u16*)alloc((size_t)NB * FD * NN * 2);
    u16* RH0m = (u16*)alloc((size_t)NB * UD * NN * 2);
    u16* RH1m = (u16*)alloc((size_t)NB * UD * NN * 2);
    u16* Zm   = (u16*)alloc((size_t)NB * UD * NN * 2);
    u16* Ut   = (u16*)alloc((size_t)NB * UD * NN * 2);
    u16* RH0f = X0f;
    u16* RH1f = X1f;

    k_rownorm<<<dim3(NN), dim3(256), 0, stream>>>(adj, d_inv);
    k_adjT<<<dim3(32, 32), dim3(256), 0, stream>>>(adj, d_inv, adjT);
    k_reorderW<<<dim3((KT * FD + 255) / 256), dim3(256), 0, stream>>>(W_ru, Wru, FD);
    k_reorderW<<<dim3((KT * UD + 255) / 256), dim3(256), 0, stream>>>(W_c, Wc, UD);
    k_xcat<<<dim3(16, NB), dim3(256), 0, stream>>>(x, hx, X0f, X0m);
    // X1 = A@X0 (dual out); Y = A@X1 (m-major only; Chebyshev folded into W)
    k_gemm<4><<<dim3(64, 16), dim3(256), 0, stream>>>(adjT, X0f, X1f, X1m, 64);
    k_gemm<4><<<dim3(64, 16), dim3(256), 0, stream>>>(adjT, X1f, nullptr, Ym, 64);
    k_proj_ru<<<dim3(16, NB), dim3(256), 0, stream>>>(X0m, X1m, Ym, Wru, b_ru, hx, RH0f, RH0m, Ut);
    // RH1 = A@RH0 (dual); Z = A@RH1 (m-major only)
    k_gemm<2><<<dim3(32, 16), dim3(256), 0, stream>>>(adjT, RH0f, RH1f, RH1m, 32);
    k_gemm<2><<<dim3(32, 16), dim3(256), 0, stream>>>(adjT, RH1f, nullptr, Zm, 32);
    k_proj_c<<<dim3(16, NB), dim3(256), 0, stream>>>(X0m, X1m, Ym, RH0m, RH1m, Zm, Wc, b_c, hx, Ut, out);
}

// Round 9
// 432.519 us; speedup vs baseline: 1.2023x; 1.0284x over previous
//
#include <hip/hip_runtime.h>
#include <math.h>

typedef __attribute__((ext_vector_type(8))) short short8;
typedef __attribute__((ext_vector_type(4))) float float4v;
typedef __attribute__((ext_vector_type(16))) float float16v;
typedef __attribute__((ext_vector_type(4))) unsigned short ushort4v;
typedef unsigned short u16;
typedef unsigned int u32;

#define NB 64
#define NN 2048
#define FD 128
#define UD 64
#define KT 384

// ---- PANEL FORMAT ----
// matrix[row][k] -> flat[(rowgrp*KGRPS + kgrp)*1024 + (((k>>3)&3)*32 + (row&31))*8 + (k&7)]
// 32x32 panel = 2KB contiguous; slot order == MFMA fragment order (lane=row, 16B/lane).
// Chebyshev fold: proj uses W0'=W0-W2, W1, W2'=2*W2 so only Y=A@X1 (not X2) is needed.

__device__ __forceinline__ u16 f2bf(float f) {
    unsigned int u = __float_as_uint(f);
    u += 0x7fffu + ((u >> 16) & 1u);
    return (u16)(u >> 16);
}
__device__ __forceinline__ float bf2f(u16 s) {
    return __uint_as_float(((unsigned int)s) << 16);
}
__device__ __forceinline__ float sigmoidf_(float x) {
    return 1.0f / (1.0f + expf(-x));
}
__device__ __forceinline__ void gl2lds16(const u16* g, u16* l) {
    __builtin_amdgcn_global_load_lds((const __attribute__((address_space(1))) unsigned int*)g,
                                     (__attribute__((address_space(3))) unsigned int*)l,
                                     16, 0, 0);
}

// ---------------------------------------------------------------- merged prep
// blocks [0,2048): rownorm | [2048,2240): reorderW ru | [2240,2336): reorderW c | [2336,3360): xcat
__global__ void k_prep(const float* __restrict__ adj, float* __restrict__ d_inv,
                       const float* __restrict__ W_ru, u16* __restrict__ Wru,
                       const float* __restrict__ W_c,  u16* __restrict__ Wc,
                       const float* __restrict__ x, const float* __restrict__ h,
                       u16* __restrict__ X0f, u16* __restrict__ X0m) {
    __shared__ u16 T[128 * 136];
    int bid = blockIdx.x;
    int t = threadIdx.x;
    if (bid < 2048) {
        // ---- rownorm
        int m = bid;
        const float4v* row = (const float4v*)(adj + (size_t)m * NN);
        float s = 0.f;
        for (int i = t; i < NN / 4; i += 256) {
            float4v v = row[i];
            s += v.x + v.y + v.z + v.w;
        }
        float* red = (float*)T;
        for (int off = 32; off; off >>= 1) s += __shfl_down(s, off, 64);
        if ((t & 63) == 0) red[t >> 6] = s;
        __syncthreads();
        if (t == 0) {
            float tt = red[0] + red[1] + red[2] + red[3] + 1.0f;
            d_inv[m] = 1.0f / tt;
        }
        return;
    }
    if (bid < 2336) {
        // ---- reorderW (Chebyshev-folded)
        const float* W; u16* Wt; int OD, idx;
        if (bid < 2240) { W = W_ru; Wt = Wru; OD = FD; idx = (bid - 2048) * 256 + t; }
        else            { W = W_c;  Wt = Wc;  OD = UD; idx = (bid - 2240) * 256 + t; }
        if (idx >= KT * OD) return;
        int o  = idx % OD;
        int kp = idx / OD;
        int kd = kp >> 7, f = kp & 127;
        float v;
        if (kd == 0)      v = W[(size_t)(f * 3 + 0) * OD + o] - W[(size_t)(f * 3 + 2) * OD + o];
        else if (kd == 1) v = W[(size_t)(f * 3 + 1) * OD + o];
        else              v = 2.0f * W[(size_t)(f * 3 + 2) * OD + o];
        size_t dst = ((size_t)(o >> 5) * 12 + (kp >> 5)) * 1024 + (((kp >> 3) & 3) * 32 + (o & 31)) * 8 + (kp & 7);
        Wt[dst] = f2bf(v);
        return;
    }
    // ---- xcat
    int rb = bid - 2336;
    int m0 = (rb & 15) * 128;
    int b  = rb >> 4;
    const float* srcs[2] = { x + (size_t)b * (NN * 64), h + (size_t)b * (NN * 64) };
    for (int s = 0; s < 2; ++s) {
        const float* src = srcs[s];
        for (int p = 0; p < 8; ++p) {
            int idx = t + 256 * p;
            int mi = idx >> 4;
            int f4 = idx & 15;
            float4v v = *(const float4v*)(src + (size_t)(m0 + mi) * 64 + f4 * 4);
            float vv[4] = {v.x, v.y, v.z, v.w};
#pragma unroll
            for (int j = 0; j < 4; ++j)
                T[(s * 64 + f4 * 4 + j) * 136 + mi] = f2bf(vv[j]);
        }
    }
    __syncthreads();
#pragma unroll
    for (int p = 0; p < 8; ++p) {
        int S = t + 256 * p;
        int fgl = S >> 9, kgl = (S >> 7) & 3, s = S & 127;
        int c = s >> 5, r = s & 31;
        short8 v = *(const short8*)(T + (fgl * 32 + r) * 136 + kgl * 32 + c * 8);
        *(short8*)(X0f + ((size_t)(b * 4 + fgl) * 64 + (m0 >> 5) + kgl) * 1024 + s * 8) = v;
    }
#pragma unroll
    for (int p = 0; p < 8; ++p) {
        int S = t + 256 * p;
        int fc = S >> 7;
        int mi = S & 127;
        short8 v;
#pragma unroll
        for (int e = 0; e < 8; ++e) v[e] = (short)T[(fc * 8 + e) * 136 + mi];
        size_t dst = ((size_t)(b * 64 + (m0 >> 5) + (mi >> 5)) * 4 + (fc >> 2)) * 1024
                     + ((fc & 3) * 32 + (mi & 31)) * 8;
        *(short8*)(X0m + dst) = v;
    }
}

// ---------------------------------------------------------------- adjT panels (rows n, k=m)
__global__ void k_adjT(const float* __restrict__ adj, const float* __restrict__ d_inv,
                       u16* __restrict__ adjT) {
    __shared__ u16 T[64 * 72];
    int m0 = blockIdx.x * 64;
    int n0 = blockIdx.y * 64;
    int t = threadIdx.x;
    for (int p = 0; p < 4; ++p) {
        int idx = t + 256 * p;
        int i  = idx >> 4;
        int n4 = idx & 15;
        int m = m0 + i;
        float4v v = *(const float4v*)(adj + (size_t)m * NN + n0 + n4 * 4);
        float di = d_inv[m];
        float vv[4] = {v.x, v.y, v.z, v.w};
#pragma unroll
        for (int j = 0; j < 4; ++j) {
            int n = n0 + n4 * 4 + j;
            float a = vv[j] + ((m == n) ? 1.0f : 0.0f);
            T[(n4 * 4 + j) * 72 + i] = f2bf(a * di);
        }
    }
    __syncthreads();
#pragma unroll
    for (int p = 0; p < 2; ++p) {
        int S = t + 256 * p;
        int rgl = S >> 8, kgl = (S >> 7) & 1, s = S & 127;
        int c = s >> 5, r = s & 31;
        short8 v = *(const short8*)(T + (rgl * 32 + r) * 72 + kgl * 32 + c * 8);
        *(short8*)(adjT + ((size_t)((n0 >> 5) + rgl) * 64 + (m0 >> 5) + kgl) * 1024 + s * 8) = v;
    }
}

// ---------------------------------------------------------------- GEMM, 128x128 tile, 32x32x16 MFMA, 4 blocks/CU
template<int FG>
__global__ __launch_bounds__(256, 4)
void k_gemm(const u16* __restrict__ A, const u16* __restrict__ Bc,
            u16* __restrict__ outF, u16* __restrict__ outM, int cBlocks) {
    __shared__ u16 SM[16384];
    u16* A0 = SM;            u16* A1 = SM + 4096;
    u16* B0 = SM + 8192;     u16* B1 = SM + 12288;

    int id = blockIdx.x + cBlocks * blockIdx.y;
    int band = cBlocks >> 3;
    int g = id & 7, s = id >> 3;
    int cb = g * band + (s % band);
    int nb = s / band;
    int c0 = cb * 128;
    int n0 = nb * 128;

    int t = threadIdx.x;
    int wave = t >> 6, lane = t & 63;
    int wy = wave & 1, wx = wave >> 1;
    int ln = lane & 31, hi = lane >> 5;
    int l16 = lane * 8;

    const u16* gaP[2];
    const u16* gbP[2];
#pragma unroll
    for (int i = 0; i < 2; ++i) {
        int T = t + 256 * i;
        gaP[i] = A  + ((size_t)((n0 >> 5) + (T >> 7)) * 64) * 1024 + (size_t)(T & 127) * 8;
        gbP[i] = Bc + ((size_t)((c0 >> 5) + (T >> 7)) * 64) * 1024 + (size_t)(T & 127) * 8;
    }

    float16v acc[2][2];
#pragma unroll
    for (int i = 0; i < 2; ++i)
#pragma unroll
        for (int j = 0; j < 2; ++j)
#pragma unroll
            for (int e = 0; e < 16; ++e) acc[i][j][e] = 0.f;

#pragma unroll
    for (int i = 0; i < 2; ++i) { gl2lds16(gaP[i], A0 + (t + 256 * i) * 8); gl2lds16(gbP[i], B0 + (t + 256 * i) * 8); }

#pragma unroll 2
    for (int it = 0; it < 64; ++it) {
        u16* Ac = (it & 1) ? A1 : A0;
        u16* Bs = (it & 1) ? B1 : B0;
        __syncthreads();
        if (it + 1 < 64) {
            int ko = (it + 1) * 1024;
            u16* An = (it & 1) ? A0 : A1;
            u16* Bn = (it & 1) ? B0 : B1;
#pragma unroll
            for (int i = 0; i < 2; ++i) { gl2lds16(gaP[i] + ko, An + (t + 256 * i) * 8); gl2lds16(gbP[i] + ko, Bn + (t + 256 * i) * 8); }
        }
        short8 fa[2][2], fb[2][2];
#pragma unroll
        for (int ks = 0; ks < 2; ++ks) {
#pragma unroll
            for (int mt = 0; mt < 2; ++mt)
                fa[ks][mt] = *(const short8*)(Bs + ((wx * 2 + mt) * 2 + ks) * 512 + l16);
#pragma unroll
            for (int nt = 0; nt < 2; ++nt)
                fb[ks][nt] = *(const short8*)(Ac + ((wy * 2 + nt) * 2 + ks) * 512 + l16);
        }
#pragma unroll
        for (int ks = 0; ks < 2; ++ks)
#pragma unroll
            for (int mt = 0; mt < 2; ++mt)
#pragma unroll
                for (int nt = 0; nt < 2; ++nt)
                    acc[mt][nt] = __builtin_amdgcn_mfma_f32_32x32x16_bf16(fa[ks][mt], fb[ks][nt], acc[mt][nt], 0, 0, 0);
    }

    // m-major direct panel writes
#pragma unroll
    for (int mt = 0; mt < 2; ++mt) {
#pragma unroll
        for (int nt = 0; nt < 2; ++nt) {
            int mg = (n0 >> 5) + wy * 2 + nt;
            int batch = (FG == 4) ? cb : (2 * cb + wx);
            int fg = (FG == 4) ? (wx * 2 + mt) : mt;
            size_t pbase = ((size_t)(batch * 64 + mg) * FG + fg) * 1024;
#pragma unroll
            for (int eq = 0; eq < 4; ++eq) {
                ushort4v pk;
#pragma unroll
                for (int r = 0; r < 4; ++r) pk[r] = f2bf(acc[mt][nt][eq * 4 + r]);
                *(ushort4v*)(outM + pbase + (eq * 32 + ln) * 8 + 4 * hi) = pk;
            }
        }
    }

    // optional f-major panels via LDS transpose
    if (outF) {
        __syncthreads();
#pragma unroll
        for (int p = 0; p < 2; ++p) {
            if (p) __syncthreads();
            if (wx == p) {
#pragma unroll
                for (int mt = 0; mt < 2; ++mt)
#pragma unroll
                    for (int nt = 0; nt < 2; ++nt)
#pragma unroll
                        for (int e = 0; e < 16; ++e) {
                            int cl = mt * 32 + 4 * hi + 8 * (e >> 2) + (e & 3);
                            int nl = wy * 64 + nt * 32 + ln;
                            SM[cl * 136 + nl] = f2bf(acc[mt][nt][e]);
                        }
            }
            __syncthreads();
#pragma unroll
            for (int pp = 0; pp < 4; ++pp) {
                int S = t + 256 * pp;
                int rgl = S >> 9, kgl = (S >> 7) & 3, sl = S & 127;
                int c = sl >> 5, r = sl & 31;
                short8 v = *(const short8*)(SM + (rgl * 32 + r) * 136 + kgl * 32 + c * 8);
                size_t gaddr = ((size_t)((c0 >> 5) + p * 2 + rgl) * 64 + (n0 >> 5) + kgl) * 1024 + sl * 8;
                *(short8*)(outF + gaddr) = v;
            }
        }
    }
}

// ---------------------------------------------------------------- ru projection: 128m x 128o, K=384, fused sigmoid
__global__ __launch_bounds__(256, 3)
void k_proj_ru(const u16* __restrict__ X0m, const u16* __restrict__ X1m, const u16* __restrict__ Ym,
               const u16* __restrict__ Wp, const float* __restrict__ bias, const float* __restrict__ hx,
               u16* __restrict__ RH0f, u16* __restrict__ RH0m, u16* __restrict__ Ut) {
    __shared__ u16 SM[16384];
    u16 *Xa = SM, *Xb = SM + 4096, *Wa = SM + 8192, *Wb = SM + 12288;
    int mb = blockIdx.x, b = blockIdx.y;
    int m0 = mb * 128, mg0 = mb * 4;
    int t = threadIdx.x, wave = t >> 6, lane = t & 63;
    int wx = wave & 1, wyy = wave >> 1;
    int ln = lane & 31, hi = lane >> 5;
    const u16* Xs[3] = {X0m, X1m, Ym};
    int p0 = t >> 7, s0 = t & 127;

    float16v acc[2][2];
#pragma unroll
    for (int i = 0; i < 2; ++i)
#pragma unroll
        for (int j = 0; j < 2; ++j)
#pragma unroll
            for (int e = 0; e < 16; ++e) acc[i][j][e] = 0.f;

    gl2lds16(Xs[0] + ((size_t)((b * 64 + mg0 + p0) * 4)) * 1024 + s0 * 8, Xa + t * 8);
    gl2lds16(Xs[0] + ((size_t)((b * 64 + mg0 + p0 + 2) * 4)) * 1024 + s0 * 8, Xa + (t + 256) * 8);
    gl2lds16(Wp + ((size_t)(p0 * 12)) * 1024 + s0 * 8, Wa + t * 8);
    gl2lds16(Wp + ((size_t)((p0 + 2) * 12)) * 1024 + s0 * 8, Wa + (t + 256) * 8);

    for (int kq = 0; kq < 12; ++kq) {
        u16* Xc = (kq & 1) ? Xb : Xa;
        u16* Wc = (kq & 1) ? Wb : Wa;
        __syncthreads();
        if (kq + 1 < 12) {
            int k2 = kq + 1, kd = k2 >> 2, kg = k2 & 3;
            u16* Xn = (kq & 1) ? Xa : Xb;
            u16* Wn = (kq & 1) ? Wa : Wb;
            const u16* xb = Xs[kd];
            gl2lds16(xb + ((size_t)((b * 64 + mg0 + p0) * 4 + kg)) * 1024 + s0 * 8, Xn + t * 8);
            gl2lds16(xb + ((size_t)((b * 64 + mg0 + p0 + 2) * 4 + kg)) * 1024 + s0 * 8, Xn + (t + 256) * 8);
            gl2lds16(Wp + ((size_t)(p0 * 12 + k2)) * 1024 + s0 * 8, Wn + t * 8);
            gl2lds16(Wp + ((size_t)((p0 + 2) * 12 + k2)) * 1024 + s0 * 8, Wn + (t + 256) * 8);
        }
        short8 fa[2][2], fb[2][2];
#pragma unroll
        for (int ks = 0; ks < 2; ++ks) {
#pragma unroll
            for (int mt = 0; mt < 2; ++mt)
                fa[ks][mt] = *(const short8*)(Xc + ((wx * 2 + mt) * 2 + ks) * 512 + lane * 8);
#pragma unroll
            for (int nt = 0; nt < 2; ++nt)
                fb[ks][nt] = *(const short8*)(Wc + ((wyy * 2 + nt) * 2 + ks) * 512 + lane * 8);
        }
#pragma unroll
        for (int ks = 0; ks < 2; ++ks)
#pragma unroll
            for (int mt = 0; mt < 2; ++mt)
#pragma unroll
                for (int nt = 0; nt < 2; ++nt)
                    acc[mt][nt] = __builtin_amdgcn_mfma_f32_32x32x16_bf16(fa[ks][mt], fb[ks][nt], acc[mt][nt], 0, 0, 0);
    }
    __syncthreads();
    if (wyy == 0) {
#pragma unroll
        for (int mt = 0; mt < 2; ++mt)
#pragma unroll
            for (int nt = 0; nt < 2; ++nt) {
                int o = nt * 32 + ln;
                float bo = bias[o];
                u16 vals[16];
#pragma unroll
                for (int e = 0; e < 16; ++e) {
                    int ml = wx * 64 + mt * 32 + 4 * hi + 8 * (e >> 2) + (e & 3);
                    float sg = sigmoidf_(acc[mt][nt][e] + bo);
                    float hh = hx[((size_t)b * NN + m0 + ml) * 64 + o];
                    vals[e] = f2bf(sg * hh);
                    SM[ml * 76 + o] = vals[e];
                }
#pragma unroll
                for (int eq = 0; eq < 4; ++eq) {
                    ushort4v pk;
#pragma unroll
                    for (int r = 0; r < 4; ++r) pk[r] = vals[eq * 4 + r];
                    size_t addr = ((size_t)(b * 2 + nt) * 64 + mg0 + wx * 2 + mt) * 1024 + (eq * 32 + ln) * 8 + 4 * hi;
                    *(ushort4v*)(RH0f + addr) = pk;
                }
            }
    } else {
#pragma unroll
        for (int mt = 0; mt < 2; ++mt)
#pragma unroll
            for (int nt = 0; nt < 2; ++nt) {
                int og = nt * 32 + ln;
                float bo = bias[64 + og];
#pragma unroll
                for (int e = 0; e < 16; ++e) {
                    int ml = wx * 64 + mt * 32 + 4 * hi + 8 * (e >> 2) + (e & 3);
                    Ut[((size_t)b * NN + m0 + ml) * 64 + og] = f2bf(sigmoidf_(acc[mt][nt][e] + bo));
                }
            }
    }
    __syncthreads();
#pragma unroll
    for (int j = 0; j < 4; ++j) {
        int C = t + 256 * j;
        int p = C >> 7, sl = C & 127;
        int mgl = p >> 1, ug = p & 1;
        int cq = sl >> 5, r = sl & 31;
        short8 v = *(const short8*)(SM + (mgl * 32 + r) * 76 + ug * 32 + cq * 8);
        *(short8*)(RH0m + ((size_t)((b * 64 + mg0 + mgl) * 2 + ug)) * 1024 + sl * 8) = v;
    }
}

// ---------------------------------------------------------------- c projection: 128m x 64o, K=384, fused tanh + combine
__global__ __launch_bounds__(256, 4)
void k_proj_c(const u16* __restrict__ X0m, const u16* __restrict__ X1m, const u16* __restrict__ Ym,
              const u16* __restrict__ RH0m, const u16* __restrict__ RH1m, const u16* __restrict__ Zm,
              const u16* __restrict__ Wp, const float* __restrict__ bias,
              const float* __restrict__ hx, const u16* __restrict__ Ut,
              float* __restrict__ out) {
    __shared__ u16 SM[12288];
    u16 *Xa = SM, *Xb = SM + 4096, *Wa = SM + 8192, *Wb = SM + 10240;
    int mb = blockIdx.x, b = blockIdx.y;
    int m0 = mb * 128, mg0 = mb * 4;
    int t = threadIdx.x, wave = t >> 6, lane = t & 63;
    int wx = wave & 1, wyy = wave >> 1;
    int ln = lane & 31, hi = lane >> 5;
    const u16* Xs[3] = {X0m, X1m, Ym};
    const u16* Rs[3] = {RH0m, RH1m, Zm};
    int p0 = t >> 7, s0 = t & 127;

    float16v acc[2];
#pragma unroll
    for (int i = 0; i < 2; ++i)
#pragma unroll
        for (int e = 0; e < 16; ++e) acc[i][e] = 0.f;

    gl2lds16(Xs[0] + ((size_t)((b * 64 + mg0 + p0) * 4)) * 1024 + s0 * 8, Xa + t * 8);
    gl2lds16(Xs[0] + ((size_t)((b * 64 + mg0 + p0 + 2) * 4)) * 1024 + s0 * 8, Xa + (t + 256) * 8);
    gl2lds16(Wp + ((size_t)(p0 * 12)) * 1024 + s0 * 8, Wa + t * 8);

    for (int kq = 0; kq < 12; ++kq) {
        u16* Xc = (kq & 1) ? Xb : Xa;
        u16* Wc = (kq & 1) ? Wb : Wa;
        __syncthreads();
        if (kq + 1 < 12) {
            int k2 = kq + 1, kd = k2 >> 2, fb2 = (k2 & 3) * 32;
            u16* Xn = (kq & 1) ? Xa : Xb;
            u16* Wn = (kq & 1) ? Wa : Wb;
            const u16* mat; size_t pb0, pb1;
            if (fb2 < 64) {
                mat = Xs[kd];
                pb0 = ((size_t)((b * 64 + mg0 + p0) * 4 + (fb2 >> 5))) * 1024;
                pb1 = ((size_t)((b * 64 + mg0 + p0 + 2) * 4 + (fb2 >> 5))) * 1024;
            } else {
                mat = Rs[kd];
                pb0 = ((size_t)((b * 64 + mg0 + p0) * 2 + ((fb2 >> 5) - 2))) * 1024;
                pb1 = ((size_t)((b * 64 + mg0 + p0 + 2) * 2 + ((fb2 >> 5) - 2))) * 1024;
            }
            gl2lds16(mat + pb0 + s0 * 8, Xn + t * 8);
            gl2lds16(mat + pb1 + s0 * 8, Xn + (t + 256) * 8);
            gl2lds16(Wp + ((size_t)(p0 * 12 + k2)) * 1024 + s0 * 8, Wn + t * 8);
        }
        short8 fa[2][2], fbg[2];
#pragma unroll
        for (int ks = 0; ks < 2; ++ks) {
#pragma unroll
            for (int mt = 0; mt < 2; ++mt)
                fa[ks][mt] = *(const short8*)(Xc + ((wx * 2 + mt) * 2 + ks) * 512 + lane * 8);
            fbg[ks] = *(const short8*)(Wc + (wyy * 2 + ks) * 512 + lane * 8);
        }
#pragma unroll
        for (int ks = 0; ks < 2; ++ks)
#pragma unroll
            for (int mt = 0; mt < 2; ++mt)
                acc[mt] = __builtin_amdgcn_mfma_f32_32x32x16_bf16(fa[ks][mt], fbg[ks], acc[mt], 0, 0, 0);
    }
    int o = wyy * 32 + ln;
    float bo = bias[o];
#pragma unroll
    for (int mt = 0; mt < 2; ++mt)
#pragma unroll
        for (int e = 0; e < 16; ++e) {
            int ml = wx * 64 + mt * 32 + 4 * hi + 8 * (e >> 2) + (e & 3);
            size_t idx = ((size_t)b * NN + m0 + ml) * 64 + o;
            float c = tanhf(acc[mt][e] + bo);
            float u = bf2f(Ut[idx]);
            float hh = hx[idx];
            out[idx] = u * hh + (1.0f - u) * c;
        }
}

// ---------------------------------------------------------------- launch
extern "C" void kernel_launch(void* const* d_in, const int* in_sizes, int n_in,
                              void* d_out, int out_size, void* d_ws, size_t ws_size,
                              hipStream_t stream) {
    const float* x    = (const float*)d_in[0];
    const float* hx   = (const float*)d_in[1];
    const float* adj  = (const float*)d_in[2];
    const float* W_ru = (const float*)d_in[3];
    const float* b_ru = (const float*)d_in[4];
    const float* W_c  = (const float*)d_in[5];
    const float* b_c  = (const float*)d_in[6];
    float* out = (float*)d_out;

    char* ws = (char*)d_ws;
    size_t off = 0;
    auto alloc = [&](size_t bytes) -> void* {
        void* p = ws + off;
        off += (bytes + 255) & ~(size_t)255;
        return p;
    };
    float* d_inv = (float*)alloc((size_t)NN * 4);
    u16* adjT = (u16*)alloc((size_t)NN * NN * 2);
    u16* Wru  = (u16*)alloc((size_t)FD * KT * 2);
    u16* Wc   = (u16*)alloc((size_t)UD * KT * 2);
    u16* X0f = (u16*)alloc((size_t)NB * FD * NN * 2);   // aliased as RH0f after gemm#1
    u16* X1f = (u16*)alloc((size_t)NB * FD * NN * 2);   // aliased as RH1f after gemm#2
    u16* X0m = (u16*)alloc((size_t)NB * FD * NN * 2);
    u16* X1m = (u16*)alloc((size_t)NB * FD * NN * 2);
    u16* Ym  = (u16*)alloc((size_t)NB * FD * NN * 2);
    u16* RH0m = (u16*)alloc((size_t)NB * UD * NN * 2);
    u16* RH1m = (u16*)alloc((size_t)NB * UD * NN * 2);
    u16* Zm   = (u16*)alloc((size_t)NB * UD * NN * 2);
    u16* Ut   = (u16*)alloc((size_t)NB * UD * NN * 2);
    u16* RH0f = X0f;
    u16* RH1f = X1f;

    // merged prep: rownorm | reorderW(ru) | reorderW(c) | xcat  (all independent)
    k_prep<<<dim3(3360), dim3(256), 0, stream>>>(adj, d_inv, W_ru, Wru, W_c, Wc, x, hx, X0f, X0m);
    k_adjT<<<dim3(32, 32), dim3(256), 0, stream>>>(adj, d_inv, adjT);
    // X1 = A@X0 (dual out); Y = A@X1 (m-major only; Chebyshev folded into W)
    k_gemm<4><<<dim3(64, 16), dim3(256), 0, stream>>>(adjT, X0f, X1f, X1m, 64);
    k_gemm<4><<<dim3(64, 16), dim3(256), 0, stream>>>(adjT, X1f, nullptr, Ym, 64);
    k_proj_ru<<<dim3(16, NB), dim3(256), 0, stream>>>(X0m, X1m, Ym, Wru, b_ru, hx, RH0f, RH0m, Ut);
    // RH1 = A@RH0 (dual); Z = A@RH1 (m-major only)
    k_gemm<2><<<dim3(32, 16), dim3(256), 0, stream>>>(adjT, RH0f, RH1f, RH1m, 32);
    k_gemm<2><<<dim3(32, 16), dim3(256), 0, stream>>>(adjT, RH1f, nullptr, Zm, 32);
    k_proj_c<<<dim3(16, NB), dim3(256), 0, stream>>>(X0m, X1m, Ym, RH0m, RH1m, Zm, Wc, b_c, hx, Ut, out);
}